// Round 15
// baseline (2263.994 us; speedup 1.0000x reference)
//
#include <hip/hip_runtime.h>

#define DINLINE __device__ __forceinline__

#define Bc 2
#define LENc 13294
#define Cc 256
#define NHc 8
#define NQc 300
#define Lc 6
#define FFc 1024

typedef unsigned short u16;
typedef __attribute__((ext_vector_type(8))) short bshort8;
typedef __attribute__((ext_vector_type(8))) unsigned short ushort8v;
typedef __attribute__((ext_vector_type(4))) float f32x4;
typedef __attribute__((ext_vector_type(2))) float f32x2;

DINLINE float bf2f(u16 u) { return __uint_as_float(((unsigned)u) << 16); }
DINLINE u16 f2bf(float f) {
  unsigned u = __float_as_uint(f);
  return (u16)((u + 0x7fffu + ((u >> 16) & 1u)) >> 16);
}
// one u32 = 2 packed bf16 channels -> 2 f32 in 2 bit-ops (exact)
DINLINE f32x2 cvt2(unsigned u) {
  f32x2 r;
  r.x = __uint_as_float(u << 16);
  r.y = __uint_as_float(u & 0xffff0000u);
  return r;
}
DINLINE void glds16(const u16* g, u16* l) {
  __builtin_amdgcn_global_load_lds((const __attribute__((address_space(1))) void*)g,
                                   (__attribute__((address_space(3))) void*)l, 16, 0, 0);
}

// ============ packed f32 -> bf16 weight conversion ============
struct WPack {
  const float* src[14];
  int off4[15];
};
__global__ void convert_weights_kernel(WPack p, u16* __restrict__ dst) {
  int i4 = blockIdx.x * 256 + threadIdx.x;
  if (i4 >= p.off4[14]) return;
  int t = 0;
#pragma unroll
  for (int k = 0; k < 13; ++k) t += (i4 >= p.off4[k + 1]) ? 1 : 0;
  int local = i4 - p.off4[t];
  float4 v = *(const float4*)(p.src[t] + (size_t)local * 4);
  ushort4 o;
  o.x = f2bf(v.x); o.y = f2bf(v.y); o.z = f2bf(v.z); o.w = f2bf(v.w);
  *(ushort4*)(dst + (size_t)i4 * 4) = o;
}

// ============ MFMA GEMM 128x128, double-buffered, XCD-swizzled ============
// flags: bit0 relu, bit1 bf16 out, bit2 head-transposed bf16 out, bit3 fused off/aw
// bf16 epilogue: 1-pass 128x128 LDS stage, quad-XOR bank swizzle.
// tpose store remap: 16-lane runs walk (pix,cc) within one head plane.
__global__ __launch_bounds__(256) void gemm_mfma_kernel(
    const u16* __restrict__ X, const u16* __restrict__ W, const float* __restrict__ bias,
    float* __restrict__ Yf, u16* __restrict__ Yb, int M, int N, int K, int flags,
    const u16* __restrict__ W2, const float* __restrict__ bias2, float* __restrict__ Yf2) {
  __shared__ __align__(16) u16 lds[2][8256];
  const int tid = threadIdx.x;
  int bx = blockIdx.x, by = blockIdx.y;
  {
    const int nx = gridDim.x, ny = gridDim.y;
    if ((ny & 7) == 0) {
      int d = by * nx + bx;
      int grp = nx << 3;                 // 8 m-rows x all n per group
      int r = d % grp, q = d / grp;
      by = (r & 7) + (q << 3);
      bx = r >> 3;
    }
  }
  const int m0 = by << 7, n0 = bx << 7;
  const int w = tid >> 6, lane = tid & 63;
  const int wm = (w & 1) << 6, wn = (w >> 1) << 6;
  const int lane15 = lane & 15, quad = lane >> 4;
  const bool fus = (flags & 8) != 0;
  const bool sec = fus && (n0 >= 256);
  const u16* Wb = sec ? W2 : W;
  const int nb0 = sec ? n0 - 256 : n0;
  f32x4 acc[4][4] = {};

  int gmA0 = m0 + lane;       if (gmA0 >= M) gmA0 = M - 1;
  int gmA1 = m0 + 64 + lane;  if (gmA1 >= M) gmA1 = M - 1;
  const u16* xa0 = X + (size_t)gmA0 * K + w * 8;
  const u16* xa1 = X + (size_t)gmA1 * K + w * 8;
  const u16* wb0 = Wb + (size_t)(nb0 + lane) * K + w * 8;
  const u16* wb1 = Wb + (size_t)(nb0 + 64 + lane) * K + w * 8;
  u16* lbase = &lds[0][0];
  const int wslot = w * 1032;

  glds16(xa0, lbase + wslot);
  glds16(xa1, lbase + wslot + 512);
  glds16(wb0, lbase + 4128 + wslot);
  glds16(wb1, lbase + 4128 + wslot + 512);
  __syncthreads();

  int cur = 0;
  for (int kt = 0; kt < K; kt += 32) {
    if (kt + 32 < K) {
      u16* nb = lbase + (cur ^ 1) * 8256;
      glds16(xa0 + kt + 32, nb + wslot);
      glds16(xa1 + kt + 32, nb + wslot + 512);
      glds16(wb0 + kt + 32, nb + 4128 + wslot);
      glds16(wb1 + kt + 32, nb + 4128 + wslot + 512);
    }
    const u16* cb = lbase + cur * 8256;
    bshort8 af[4], bfr[4];
#pragma unroll
    for (int mi = 0; mi < 4; ++mi)
      af[mi] = *(const bshort8*)&cb[quad * 1032 + (wm + mi * 16 + lane15) * 8];
#pragma unroll
    for (int ni = 0; ni < 4; ++ni)
      bfr[ni] = *(const bshort8*)&cb[4128 + quad * 1032 + (wn + ni * 16 + lane15) * 8];
#pragma unroll
    for (int mi = 0; mi < 4; ++mi)
#pragma unroll
      for (int ni = 0; ni < 4; ++ni)
        acc[mi][ni] = __builtin_amdgcn_mfma_f32_16x16x32_bf16(af[mi], bfr[ni], acc[mi][ni], 0, 0, 0);
    __syncthreads();
    cur ^= 1;
  }

  float bv[4];
#pragma unroll
  for (int ni = 0; ni < 4; ++ni) {
    int nc = nb0 + wn + ni * 16 + lane15;
    bv[ni] = sec ? bias2[nc] : bias[nc];
  }
  const int relu = flags & 1, asbf = flags & 2, tpose = flags & 4;
  const int ldy = fus ? 256 : N;

  if (asbf | tpose) {
    // ---- 1-pass LDS-staged coalesced bf16 epilogue, quad-XOR bank swizzle ----
    u16* eb = &lds[0][0];  // 128*128 = 16384 u16 <= 16512
#pragma unroll
    for (int mi = 0; mi < 4; ++mi)
#pragma unroll
      for (int reg = 0; reg < 4; ++reg) {
        int row = wm + mi * 16 + quad * 4 + reg;   // (row>>2)&3 == quad
#pragma unroll
        for (int ni = 0; ni < 4; ++ni) {
          float v = acc[mi][ni][reg] + bv[ni];
          if (relu) v = fmaxf(v, 0.f);
          int col = (wn + ni * 16 + lane15) ^ (quad << 4);
          eb[row * 128 + col] = f2bf(v);
        }
      }
    __syncthreads();
    if (tpose) {
      // 16-lane run covers 4 consecutive pix x 4 cc-chunks within ONE head plane.
      const int cc8 = (tid & 3) * 8;        // channel chunk 0,8,16,24
      const int pix4 = (tid >> 2) & 3;      // 4 consecutive rows
      const int hgi = (tid >> 4) & 3;       // head plane within the 128-col tile
#pragma unroll
      for (int pass = 0; pass < 8; ++pass) {
        int row = pass * 16 + (tid >> 6) * 4 + pix4;
        int s = (row >> 2) & 3;
        int gm = m0 + row;
        int col = hgi * 32 + cc8;
        ushort8v v = *(const ushort8v*)&eb[row * 128 + (col ^ (s << 4))];
        if (gm < M) {
          int gc = n0 + col;
          int hg = gc >> 5;
          int bb = gm / LENc, pix = gm - bb * LENc;
          *(ushort8v*)&Yb[(((size_t)hg * Bc + bb) * LENc + pix) * 32 + cc8] = v;
        }
      }
    } else {
      const int r4 = tid >> 4, cg = tid & 15;
#pragma unroll
      for (int pass = 0; pass < 8; ++pass) {
        int row = pass * 16 + r4;
        int s = (row >> 2) & 3;
        int gm = m0 + row;
        ushort8v v = *(const ushort8v*)&eb[row * 128 + ((cg * 8) ^ (s << 4))];
        if (gm < M) {
          *(ushort8v*)&Yb[(size_t)gm * ldy + n0 + cg * 8] = v;
        }
      }
    }
    return;
  }

#pragma unroll
  for (int mi = 0; mi < 4; ++mi)
#pragma unroll
    for (int reg = 0; reg < 4; ++reg) {
      int gm = m0 + wm + mi * 16 + quad * 4 + reg;
      if (gm >= M) continue;
#pragma unroll
      for (int ni = 0; ni < 4; ++ni) {
        float v = acc[mi][ni][reg] + bv[ni];
        if (relu) v = fmaxf(v, 0.f);
        int gc = nb0 + wn + ni * 16 + lane15;
        if (sec) Yf2[(size_t)gm * 128 + gc] = v;
        else Yf[(size_t)gm * ldy + gc] = v;
      }
    }
}

// ============ MFMA GEMM 64x64 (small M, decoder), double-buffered ============
// flags: bit0 relu, bit1 bf16 out, bit3 fused off/aw (sec=n0>=256, out stride 128),
//        bit4 fused sa qk+v (sec=n0>=512, X2/dout input, out stride 256)
__global__ __launch_bounds__(256) void gemm_small_kernel(
    const u16* __restrict__ X, const u16* __restrict__ W, const float* __restrict__ bias,
    float* __restrict__ Yf, u16* __restrict__ Yb, int M, int N, int K, int flags,
    const u16* __restrict__ W2, const float* __restrict__ bias2, float* __restrict__ Yf2,
    const u16* __restrict__ X2) {
  __shared__ __align__(16) u16 lds[2][4160];
  const int tid = threadIdx.x;
  const int m0 = blockIdx.y << 6, n0 = blockIdx.x << 6;
  const int w = tid >> 6, lane = tid & 63;
  const int wm = (w & 1) << 5, wn = (w >> 1) << 5;
  const int lane15 = lane & 15, quad = lane >> 4;
  const bool fus3 = (flags & 8) != 0;
  const bool fus4 = (flags & 16) != 0;
  const bool sec = (fus3 && n0 >= 256) || (fus4 && n0 >= 512);
  const int secbase = fus4 ? 512 : 256;
  const u16* Wb = sec ? W2 : W;
  const u16* Xs = (sec && fus4) ? X2 : X;
  const int nb0 = sec ? n0 - secbase : n0;
  const int ldy1 = fus3 ? 256 : (fus4 ? 512 : N);
  const int ldy2 = fus4 ? 256 : 128;
  f32x4 acc[2][2] = {};

  int gmA = m0 + lane; if (gmA >= M) gmA = M - 1;
  const u16* xa = Xs + (size_t)gmA * K + w * 8;
  const u16* wb = Wb + (size_t)(nb0 + lane) * K + w * 8;
  u16* lbase = &lds[0][0];
  const int wslot = w * 520;

  glds16(xa, lbase + wslot);
  glds16(wb, lbase + 2080 + wslot);
  __syncthreads();

  int cur = 0;
  for (int kt = 0; kt < K; kt += 32) {
    if (kt + 32 < K) {
      u16* nb = lbase + (cur ^ 1) * 4160;
      glds16(xa + kt + 32, nb + wslot);
      glds16(wb + kt + 32, nb + 2080 + wslot);
    }
    const u16* cb = lbase + cur * 4160;
    bshort8 af[2], bfr[2];
#pragma unroll
    for (int mi = 0; mi < 2; ++mi)
      af[mi] = *(const bshort8*)&cb[quad * 520 + (wm + mi * 16 + lane15) * 8];
#pragma unroll
    for (int ni = 0; ni < 2; ++ni)
      bfr[ni] = *(const bshort8*)&cb[2080 + quad * 520 + (wn + ni * 16 + lane15) * 8];
#pragma unroll
    for (int mi = 0; mi < 2; ++mi)
#pragma unroll
      for (int ni = 0; ni < 2; ++ni)
        acc[mi][ni] = __builtin_amdgcn_mfma_f32_16x16x32_bf16(af[mi], bfr[ni], acc[mi][ni], 0, 0, 0);
    __syncthreads();
    cur ^= 1;
  }

  float bv[2];
#pragma unroll
  for (int ni = 0; ni < 2; ++ni) {
    int nc = nb0 + wn + ni * 16 + lane15;
    bv[ni] = sec ? bias2[nc] : bias[nc];
  }
  const int relu = flags & 1, asbf = flags & 2;
#pragma unroll
  for (int mi = 0; mi < 2; ++mi)
#pragma unroll
    for (int reg = 0; reg < 4; ++reg) {
      int gm = m0 + wm + mi * 16 + quad * 4 + reg;
      if (gm >= M) continue;
#pragma unroll
      for (int ni = 0; ni < 2; ++ni) {
        float v = acc[mi][ni][reg] + bv[ni];
        if (relu) v = fmaxf(v, 0.f);
        int gc = nb0 + wn + ni * 16 + lane15;
        if (sec) Yf2[(size_t)gm * ldy2 + gc] = v;
        else if (asbf) Yb[(size_t)gm * ldy1 + gc] = f2bf(v);
        else Yf[(size_t)gm * ldy1 + gc] = v;
      }
    }
}

// ============ elementwise (float4) ============
// conv_in: mem=src (f32), mem_bf=f2bf(src), xattn=f2bf(src+pos)  (layer-0 input)
__global__ void conv_in_kernel(const float* __restrict__ in, const float* __restrict__ pos,
                               float* __restrict__ outf, u16* __restrict__ outb,
                               u16* __restrict__ xat, int n4) {
  int i = blockIdx.x * 256 + threadIdx.x;
  if (i >= n4) return;
  float4 v = *(const float4*)(in + (size_t)i * 4);
  float4 p = *(const float4*)(pos + (size_t)i * 4);
  *(float4*)(outf + (size_t)i * 4) = v;
  ushort4 o; o.x = f2bf(v.x); o.y = f2bf(v.y); o.z = f2bf(v.z); o.w = f2bf(v.w);
  *(ushort4*)(outb + (size_t)i * 4) = o;
  ushort4 x; x.x = f2bf(v.x + p.x); x.y = f2bf(v.y + p.y);
  x.z = f2bf(v.z + p.z); x.w = f2bf(v.w + p.w);
  *(ushort4*)(xat + (size_t)i * 4) = x;
}
__global__ void store_f32_kernel(const float* __restrict__ in, float* __restrict__ out, int n4) {
  int i = blockIdx.x * 256 + threadIdx.x;
  if (i < n4) *(float4*)(out + (size_t)i * 4) = *(const float4*)(in + (size_t)i * 4);
}

// ============ residual + LN: wave per row, float4, shfl-only ============
// Optional fused epilogue: if extra != nullptr, also writes
//   extra[row*256+c] = f2bf(y + addv[prow*256+c]) with prow = wrap ? row%wrap : row.
__global__ __launch_bounds__(256) void add_ln_kernel(
    float* __restrict__ res, const float* __restrict__ x,
    const float* __restrict__ g, const float* __restrict__ b,
    u16* __restrict__ shadow, int M,
    const float* __restrict__ addv, u16* __restrict__ extra, int wrap) {
  int row = blockIdx.x * 4 + (threadIdx.x >> 6);
  int lane = threadIdx.x & 63;
  if (row >= M) return;
  size_t base = (size_t)row * 256 + lane * 4;
  float4 rv = *(const float4*)(res + base);
  float4 xv = *(const float4*)(x + base);
  float v0 = rv.x + xv.x, v1 = rv.y + xv.y, v2 = rv.z + xv.z, v3 = rv.w + xv.w;
  float s = v0 + v1 + v2 + v3;
#pragma unroll
  for (int o = 32; o > 0; o >>= 1) s += __shfl_xor(s, o, 64);
  float mean = s * (1.f / 256.f);
  float d0 = v0 - mean, d1 = v1 - mean, d2 = v2 - mean, d3 = v3 - mean;
  float s2 = d0 * d0 + d1 * d1 + d2 * d2 + d3 * d3;
#pragma unroll
  for (int o = 32; o > 0; o >>= 1) s2 += __shfl_xor(s2, o, 64);
  float rstd = rsqrtf(s2 * (1.f / 256.f) + 1e-5f);
  float4 gv = *(const float4*)(g + lane * 4);
  float4 bv = *(const float4*)(b + lane * 4);
  float y0 = d0 * rstd * gv.x + bv.x;
  float y1 = d1 * rstd * gv.y + bv.y;
  float y2 = d2 * rstd * gv.z + bv.z;
  float y3 = d3 * rstd * gv.w + bv.w;
  float4 yo; yo.x = y0; yo.y = y1; yo.z = y2; yo.w = y3;
  *(float4*)(res + base) = yo;
  ushort4 so; so.x = f2bf(y0); so.y = f2bf(y1); so.z = f2bf(y2); so.w = f2bf(y3);
  *(ushort4*)(shadow + base) = so;
  if (extra) {
    int prow = wrap ? (row % wrap) : row;
    float4 pv = *(const float4*)(addv + (size_t)prow * 256 + lane * 4);
    ushort4 eo;
    eo.x = f2bf(y0 + pv.x); eo.y = f2bf(y1 + pv.y);
    eo.z = f2bf(y2 + pv.z); eo.w = f2bf(y3 + pv.w);
    *(ushort4*)(extra + base) = eo;
  }
}

__global__ void enc_ref_kernel(const float* __restrict__ vr, float* __restrict__ ref) {
  int idx = blockIdx.x * 256 + threadIdx.x;
  if (idx >= Bc * LENc) return;
  int b = idx / LENc, p = idx % LENc;
  int st, HW, lvl;
  if (p < 10000)      { lvl = 0; st = 0;     HW = 100; }
  else if (p < 12500) { lvl = 1; st = 10000; HW = 50; }
  else if (p < 13125) { lvl = 2; st = 12500; HW = 25; }
  else                { lvl = 3; st = 13125; HW = 13; }
  int r = p - st;
  int i = r / HW, j = r % HW;
  float vrx = vr[(b * 4 + lvl) * 2 + 0];
  float vry = vr[(b * 4 + lvl) * 2 + 1];
  float ry = (i + 0.5f) / (vry * HW);
  float rx = (j + 0.5f) / (vrx * HW);
#pragma unroll
  for (int l = 0; l < 4; ++l) {
    ref[((size_t)idx * 4 + l) * 2 + 0] = rx * vr[(b * 4 + l) * 2 + 0];
    ref[((size_t)idx * 4 + l) * 2 + 1] = ry * vr[(b * 4 + l) * 2 + 1];
  }
}

__global__ void dec_ref_kernel(const float* __restrict__ qe, const float* __restrict__ rw,
                               const float* __restrict__ rb, const float* __restrict__ vr,
                               float* __restrict__ dref) {
  int idx = blockIdx.x * 256 + threadIdx.x;
  if (idx >= NQc * 2) return;
  int qi = idx >> 1, c = idx & 1;
  float s = rb[c];
  for (int k = 0; k < 256; ++k)
    s += qe[(size_t)qi * 512 + k] * rw[c * 256 + k];
  s = 1.f / (1.f + expf(-s));
  for (int b = 0; b < Bc; ++b)
#pragma unroll
    for (int l = 0; l < 4; ++l)
      dref[(((size_t)(b * NQc + qi)) * 4 + l) * 2 + c] = s * vr[(b * 4 + l) * 2 + c];
}

// dec_init: qpos, dout (both batches), dout_bf, and qbuf_bf = f2bf(tgt + qpos)
__global__ void dec_init_kernel(const float* __restrict__ qe, float* __restrict__ qpos,
                                float* __restrict__ outf, u16* __restrict__ outb,
                                u16* __restrict__ qbuf) {
  int i = blockIdx.x * 256 + threadIdx.x;
  if (i >= NQc * Cc) return;
  int qi = i >> 8, c = i & 255;
  float qp = qe[(size_t)qi * 512 + c];
  qpos[i] = qp;
  float t = qe[(size_t)qi * 512 + 256 + c];
  outf[i] = t;
  outf[NQc * Cc + i] = t;
  u16 tb = f2bf(t);
  outb[i] = tb;
  outb[NQc * Cc + i] = tb;
  u16 qb = f2bf(t + qp);
  qbuf[i] = qb;
  qbuf[NQc * Cc + i] = qb;
}

// ============ deformable sampler v5: fused softmax + tap-parallel + shfl broadcast ======
// aw holds RAW LOGITS; softmax over the 16 (l,p) entries computed in-kernel.
__global__ __launch_bounds__(256) void deform_sample_kernel(
    const float* __restrict__ ref, const float* __restrict__ off,
    const float* __restrict__ aw, const u16* __restrict__ value_t,
    u16* __restrict__ out, int Q, int plane_base) {
  __shared__ float sOff[2048];  // 8 bq x (8 h x 32), idx ^= h*4
  __shared__ float sAw[1024];   // 8 bq x (8 h x 16), idx ^= (h>>1)*4
  __shared__ float sRef[64];    // 8 bq x 8
  const int t = threadIdx.x;
  const int bq0 = blockIdx.x * 8;
  const int nbq = Bc * Q;
#pragma unroll
  for (int it = 0; it < 2; ++it) {
    int e = (it * 256 + t) * 4;          // float idx: bqL*256 + h*32 + k
    int bqL = e >> 8;
    int hh = (e >> 5) & 7;
    int sbq = bq0 + bqL; if (sbq >= nbq) sbq = nbq - 1;
    float4 v = *(const float4*)(off + (size_t)sbq * 256 + (e & 255));
    *(float4*)&sOff[e ^ (hh << 2)] = v;
  }
  {
    int e = t * 4;                       // float idx: bqL*128 + h*16 + j
    int bqL = e >> 7;
    int hh = (e >> 4) & 7;
    int sbq = bq0 + bqL; if (sbq >= nbq) sbq = nbq - 1;
    float4 v = *(const float4*)(aw + (size_t)sbq * 128 + (e & 127));
    *(float4*)&sAw[e ^ ((hh >> 1) << 2)] = v;
  }
  if (t < 16) {
    int bqL = t >> 1;
    int sbq = bq0 + bqL; if (sbq >= nbq) sbq = nbq - 1;
    float4 v = *(const float4*)(ref + (size_t)sbq * 8 + (t & 1) * 4);
    *(float4*)&sRef[t * 4] = v;
  }
  __syncthreads();
  const int c8 = t & 3;
  const int h = (t >> 2) & 7;
  const int bqL = t >> 5;
  const int bq = bq0 + bqL;
  if (bq >= nbq) return;
  const int b = bq / Q;
  const int HWs[4] = {100, 50, 25, 13};
  const int starts[4] = {0, 10000, 12500, 13125};
  const float* sOb = &sOff[(bqL << 8) + (h << 5)];
  const float* sAb = &sAw[(bqL << 7) + (h << 4)];
  const float* sRb = &sRef[bqL << 3];
  const int hswo = h << 2;
  const int hswa = (h >> 1) << 2;
  const u16* vplane = value_t + ((size_t)(plane_base + h) * Bc + b) * LENc * 32 + c8 * 8;

  // ---- fused softmax over the unit's 16 logits (4 per lane x 4-lane group) ----
  float lg[4];
#pragma unroll
  for (int l = 0; l < 4; ++l) lg[l] = sAb[(l * 4 + c8) ^ hswa];
  float mx = fmaxf(fmaxf(lg[0], lg[1]), fmaxf(lg[2], lg[3]));
  mx = fmaxf(mx, __shfl_xor(mx, 1, 64));
  mx = fmaxf(mx, __shfl_xor(mx, 2, 64));
  float ew[4];
  float ssum = 0.f;
#pragma unroll
  for (int l = 0; l < 4; ++l) { ew[l] = expf(lg[l] - mx); ssum += ew[l]; }
  ssum += __shfl_xor(ssum, 1, 64);
  ssum += __shfl_xor(ssum, 2, 64);
  const float sinv = 1.f / ssum;

  // ---- Phase A: this lane computes tap (l, p=c8) for l=0..3 ----
  float tw00[4], tw10[4], tw01[4], tw11[4];
  int tp00[4], tp10[4], tp01[4], tp11[4];
#pragma unroll
  for (int l = 0; l < 4; ++l) {
    const int HW = HWs[l];
    const float HWf = (float)HW;
    const int st = starts[l];
    const int p = c8;
    float rx = sRb[l * 2 + 0], ry = sRb[l * 2 + 1];
    float ox = sOb[((l * 4 + p) * 2 + 0) ^ hswo];
    float oy = sOb[((l * 4 + p) * 2 + 1) ^ hswo];
    float wgt = ew[l] * sinv;
    float x = rx * HWf + ox - 0.5f;
    float y = ry * HWf + oy - 0.5f;
    float xf = floorf(x), yf = floorf(y);
    float wx = x - xf, wy = y - yf;
    int x0 = (int)xf, y0 = (int)yf;
    bool vx0 = ((unsigned)x0 < (unsigned)HW);
    bool vx1 = ((unsigned)(x0 + 1) < (unsigned)HW);
    bool vy0 = ((unsigned)y0 < (unsigned)HW);
    bool vy1 = ((unsigned)(y0 + 1) < (unsigned)HW);
    int xc0 = min(max(x0, 0), HW - 1);
    int xc1 = min(max(x0 + 1, 0), HW - 1);
    int yc0 = min(max(y0, 0), HW - 1);
    int yc1 = min(max(y0 + 1, 0), HW - 1);
    tw00[l] = (vx0 & vy0) ? (1.f - wx) * (1.f - wy) * wgt : 0.f;
    tw10[l] = (vx1 & vy0) ? wx * (1.f - wy) * wgt : 0.f;
    tw01[l] = (vx0 & vy1) ? (1.f - wx) * wy * wgt : 0.f;
    tw11[l] = (vx1 & vy1) ? wx * wy * wgt : 0.f;
    int r0 = (st + yc0 * HW) << 5;
    int r1 = (st + yc1 * HW) << 5;
    tp00[l] = r0 + (xc0 << 5);
    tp10[l] = r0 + (xc1 << 5);
    tp01[l] = r1 + (xc0 << 5);
    tp11[l] = r1 + (xc1 << 5);
  }

  // ---- Phase B: gather + accumulate; tap data broadcast from lane (base|p) ----
  const int lnbase = t & ~3;  // within-wave group base (shfl uses block-lane id mod 64)
  f32x2 a2[4] = {};
#pragma unroll
  for (int l = 0; l < 4; ++l) {
#pragma unroll
    for (int p = 0; p < 4; ++p) {
      const int src = lnbase + p;
      float w00 = __shfl(tw00[l], src, 64);
      float w10 = __shfl(tw10[l], src, 64);
      float w01 = __shfl(tw01[l], src, 64);
      float w11 = __shfl(tw11[l], src, 64);
      int p00 = __shfl(tp00[l], src, 64);
      int p10 = __shfl(tp10[l], src, 64);
      int p01 = __shfl(tp01[l], src, 64);
      int p11 = __shfl(tp11[l], src, 64);
      const uint4 q00 = *(const uint4*)(vplane + p00);
      const uint4 q10 = *(const uint4*)(vplane + p10);
      const uint4 q01 = *(const uint4*)(vplane + p01);
      const uint4 q11 = *(const uint4*)(vplane + p11);
      f32x2 w002 = {w00, w00}, w102 = {w10, w10}, w012 = {w01, w01}, w112 = {w11, w11};
      a2[0] += w002 * cvt2(q00.x) + w102 * cvt2(q10.x) + w012 * cvt2(q01.x) + w112 * cvt2(q11.x);
      a2[1] += w002 * cvt2(q00.y) + w102 * cvt2(q10.y) + w012 * cvt2(q01.y) + w112 * cvt2(q11.y);
      a2[2] += w002 * cvt2(q00.z) + w102 * cvt2(q10.z) + w012 * cvt2(q01.z) + w112 * cvt2(q11.z);
      a2[3] += w002 * cvt2(q00.w) + w102 * cvt2(q10.w) + w012 * cvt2(q01.w) + w112 * cvt2(q11.w);
    }
  }
  ushort8v o;
#pragma unroll
  for (int j = 0; j < 4; ++j) {
    o[2 * j] = f2bf(a2[j].x);
    o[2 * j + 1] = f2bf(a2[j].y);
  }
  *(ushort8v*)(out + (size_t)bq * 256 + h * 32 + c8 * 8) = o;
}

// ============ decoder self-attention core (qk stride 512) ============
// PV phase: 2-way j-split across lane halves (all 64 lanes active), combined
// via one shfl_xor(32) -- halves the 300-iter serial load chain.
__global__ __launch_bounds__(256) void mha_core_kernel(
    const float* __restrict__ qk, const float* __restrict__ v, u16* __restrict__ out) {
  __shared__ float sc[4][304];
  int wslot = threadIdx.x >> 6;
  int lane = threadIdx.x & 63;
  int w = blockIdx.x * 4 + wslot;
  if (w >= Bc * NHc * NQc) return;
  int b = w / (NHc * NQc);
  int rem = w % (NHc * NQc);
  int h = rem / NQc;
  int qi = rem % NQc;
  const float scale = 0.1767766952966369f;
  float qv[32];
  const float* qptr = qk + ((size_t)(b * NQc + qi)) * 512 + h * 32;
#pragma unroll
  for (int d = 0; d < 32; ++d) qv[d] = qptr[d];
  float mx = -1e30f;
  for (int j = lane; j < NQc; j += 64) {
    const float* kptr = qk + ((size_t)(b * NQc + j)) * 512 + 256 + h * 32;
    float s = 0.f;
#pragma unroll
    for (int d = 0; d < 32; ++d) s += qv[d] * kptr[d];
    s *= scale;
    sc[wslot][j] = s;
    mx = fmaxf(mx, s);
  }
#pragma unroll
  for (int o = 32; o > 0; o >>= 1) mx = fmaxf(mx, __shfl_xor(mx, o, 64));
  float se = 0.f;
  for (int j = lane; j < NQc; j += 64) {
    float e = expf(sc[wslot][j] - mx);
    sc[wslot][j] = e;
    se += e;
  }
#pragma unroll
  for (int o = 32; o > 0; o >>= 1) se += __shfl_xor(se, o, 64);
  float inv = 1.f / se;
  // PV: lanes 0-31 handle even j, lanes 32-63 odd j; combine with xor-32.
  const int half = lane >> 5;
  const int d = lane & 31;
  float acc = 0.f;
  for (int j = half; j < NQc; j += 2)
    acc += sc[wslot][j] * v[((size_t)(b * NQc + j)) * 256 + h * 32 + d];
  acc += __shfl_xor(acc, 32, 64);
  if (lane < 32)
    out[((size_t)(b * NQc + qi)) * 256 + h * 32 + d] = f2bf(acc * inv);
}

// ============ host ============
static inline int cdiv_i(int a, int b) { return (a + b - 1) / b; }

#define WE_OFF   0
#define WE_AW    393216
#define WE_VAL   589824
#define WE_OUT   983040
#define WE_F1    1376256
#define WE_F2    2949120
#define WD_SAIN  4521984
#define WD_SAOUT 5701632
#define WD_OFF   6094848
#define WD_AW    6488064
#define WD_VAL   6684672
#define WD_OUT   7077888
#define WD_F1    7471104
#define WD_F2    9043968
#define W_TOTAL  10616832

extern "C" void kernel_launch(void* const* d_in, const int* in_sizes, int n_in,
                              void* d_out, int out_size, void* d_ws, size_t ws_size,
                              hipStream_t stream) {
  (void)in_sizes; (void)n_in;
  const float* src_p = (const float*)d_in[0];
  const float* pos_p = (const float*)d_in[1];
  const float* qe_p = (const float*)d_in[2];
  const float* vr_p = (const float*)d_in[3];
  const float* e_off_w = (const float*)d_in[4];  const float* e_off_b = (const float*)d_in[5];
  const float* e_aw_w = (const float*)d_in[6];   const float* e_aw_b = (const float*)d_in[7];
  const float* e_val_w = (const float*)d_in[8];  const float* e_val_b = (const float*)d_in[9];
  const float* e_out_w = (const float*)d_in[10]; const float* e_out_b = (const float*)d_in[11];
  const float* e_f1_w = (const float*)d_in[12];  const float* e_f1_b = (const float*)d_in[13];
  const float* e_f2_w = (const float*)d_in[14];  const float* e_f2_b = (const float*)d_in[15];
  const float* d_sa_in_w = (const float*)d_in[16];  const float* d_sa_in_b = (const float*)d_in[17];
  const float* d_sa_out_w = (const float*)d_in[18]; const float* d_sa_out_b = (const float*)d_in[19];
  const float* d_off_w = (const float*)d_in[20]; const float* d_off_b = (const float*)d_in[21];
  const float* d_aw_w = (const float*)d_in[22];  const float* d_aw_b = (const float*)d_in[23];
  const float* d_val_w = (const float*)d_in[24]; const float* d_val_b = (const float*)d_in[25];
  const float* d_out_w = (const float*)d_in[26]; const float* d_out_b = (const float*)d_in[27];
  const float* d_f1_w = (const float*)d_in[28];  const float* d_f1_b = (const float*)d_in[29];
  const float* d_f2_w = (const float*)d_in[30];  const float* d_f2_b = (const float*)d_in[31];
  const float* ref_w = (const float*)d_in[32];   const float* ref_b = (const float*)d_in[33];
  const float* e_ln1_g = (const float*)d_in[34]; const float* e_ln1_b = (const float*)d_in[35];
  const float* e_ln2_g = (const float*)d_in[36]; const float* e_ln2_b = (const float*)d_in[37];
  const float* d_ln1_g = (const float*)d_in[38]; const float* d_ln1_b = (const float*)d_in[39];
  const float* d_ln2_g = (const float*)d_in[40]; const float* d_ln2_b = (const float*)d_in[41];
  const float* d_ln3_g = (const float*)d_in[42]; const float* d_ln3_b = (const float*)d_in[43];

  const size_t BLC = (size_t)Bc * LENc * Cc;
  float* ws = (float*)d_ws;

  float* mem = ws;                       // BLC (dead after encoder+value6)
  float* bufA = mem + BLC;               // BLC
  float* U = bufA + BLC;                 // 2.5*BLC
  float* encref = U + (5 * BLC / 2);
  float* qpos = encref + (size_t)Bc * LENc * 8;
  float* doutb = qpos + (size_t)NQc * Cc;
  float* qkb = doutb + (size_t)Bc * NQc * Cc;
  float* dvb = qkb + (size_t)Bc * NQc * 512;
  float* drefb = dvb + (size_t)Bc * NQc * Cc;
  float* doffb = drefb + (size_t)Bc * NQc * 8;
  float* dawb = doffb + (size_t)Bc * NQc * Cc;
  float* dproj = dawb + (size_t)Bc * NQc * 128;
  float* after = dproj + (size_t)Bc * NQc * Cc;
  u16* mem_bf = (u16*)after;
  u16* qbuf_bf = mem_bf + BLC;
  u16* dout_bf = qbuf_bf + (size_t)Bc * NQc * Cc;
  u16* dattn_bf = dout_bf + (size_t)Bc * NQc * Cc;
  u16* dhid_bf = dattn_bf + (size_t)Bc * NQc * Cc;
  u16* wbf = dhid_bf + (size_t)Bc * NQc * FFc;
  u16* bf_end = wbf + W_TOTAL;
  // encoder-phase union members (in U)
  float* offb = U;
  float* awb = U + BLC;
  u16* value_bf = (u16*)(U + 3 * BLC / 2);
  u16* xattn_bf = (u16*)(U + 2 * BLC);
  u16* hid_bf = (u16*)U;
  // decoder-phase: batched value projections in dead encoder region
  u16* value6_bf = (u16*)ws;

  size_t total_bytes = (size_t)((char*)bf_end - (char*)d_ws);
  if (ws_size < total_bytes) return;

  const int Mrows = Bc * LENc;  // 26588
  const int Mdec = Bc * NQc;    // 600
  const int EB = 256;

  WPack wp;
  wp.src[0] = e_off_w;   wp.src[1] = e_aw_w;    wp.src[2] = e_val_w;  wp.src[3] = e_out_w;
  wp.src[4] = e_f1_w;    wp.src[5] = e_f2_w;    wp.src[6] = d_sa_in_w; wp.src[7] = d_sa_out_w;
  wp.src[8] = d_off_w;   wp.src[9] = d_aw_w;    wp.src[10] = d_val_w; wp.src[11] = d_out_w;
  wp.src[12] = d_f1_w;   wp.src[13] = d_f2_w;
  const int offs[15] = {WE_OFF, WE_AW, WE_VAL, WE_OUT, WE_F1, WE_F2, WD_SAIN, WD_SAOUT,
                        WD_OFF, WD_AW, WD_VAL, WD_OUT, WD_F1, WD_F2, W_TOTAL};
  for (int k = 0; k < 15; ++k) wp.off4[k] = offs[k] / 4;
  convert_weights_kernel<<<cdiv_i(W_TOTAL / 4, EB), EB, 0, stream>>>(wp, wbf);

  auto gemm = [&](const u16* Xp, const u16* Wp, const float* bp, float* Yf, u16* Yb,
                  int M, int N, int K, int flags) {
    dim3 g(N / 128, cdiv_i(M, 128));
    gemm_mfma_kernel<<<g, dim3(256), 0, stream>>>(Xp, Wp, bp, Yf, Yb, M, N, K, flags,
                                                  nullptr, nullptr, nullptr);
  };
  auto gemm_fused = [&](const u16* Xp, const u16* Wp, const float* bp, float* Yf,
                        const u16* W2p, const float* b2p, float* Yf2, int M, int K) {
    dim3 g(3, cdiv_i(M, 128));  // N = 384
    gemm_mfma_kernel<<<g, dim3(256), 0, stream>>>(Xp, Wp, bp, Yf, nullptr, M, 384, K, 8,
                                                  W2p, b2p, Yf2);
  };
  auto gemm_s = [&](const u16* Xp, const u16* Wp, const float* bp, float* Yf, u16* Yb,
                    int M, int N, int K, int flags) {
    dim3 g(N / 64, cdiv_i(M, 64));
    gemm_small_kernel<<<g, dim3(256), 0, stream>>>(Xp, Wp, bp, Yf, Yb, M, N, K, flags,
                                                   nullptr, nullptr, nullptr, nullptr);
  };
  auto gemm_s_fused = [&](const u16* Xp, const u16* Wp, const float* bp, float* Yf,
                          const u16* W2p, const float* b2p, float* Yf2, int M, int K) {
    dim3 g(6, cdiv_i(M, 64));  // N = 384
    gemm_small_kernel<<<g, dim3(256), 0, stream>>>(Xp, Wp, bp, Yf, nullptr, M, 384, K, 8,
                                                   W2p, b2p, Yf2, nullptr);
  };
  auto gemm_s_sa = [&](const u16* Xq, const u16* Xv, const u16* Wp, const float* bp,
                       float* Yqk, float* Yv, int M, int K) {
    dim3 g(12, cdiv_i(M, 64));  // N = 768: cols 0..511 -> qk (X=Xq), 512..767 -> v (X2=Xv)
    gemm_small_kernel<<<g, dim3(256), 0, stream>>>(Xq, Wp, bp, Yqk, nullptr, M, 768, K, 16,
                                                   Wp + (size_t)512 * 256, bp + 512, Yv, Xv);
  };
  auto addln = [&](float* resp, const float* xp, const float* gp, const float* bbp,
                   u16* shp, int M, const float* addv, u16* extra, int wrap) {
    add_ln_kernel<<<cdiv_i(M, 4), dim3(256), 0, stream>>>(resp, xp, gp, bbp, shp, M,
                                                          addv, extra, wrap);
  };

  conv_in_kernel<<<cdiv_i((int)(BLC / 4), EB), EB, 0, stream>>>(
      src_p, pos_p, mem, mem_bf, xattn_bf, (int)(BLC / 4));
  enc_ref_kernel<<<cdiv_i(Bc * LENc, EB), EB, 0, stream>>>(vr_p, encref);

  // ---- encoder ----
  for (int i = 0; i < Lc; ++i) {
    const size_t oW = (size_t)i * 256 * 256, oAW = (size_t)i * 128 * 256, oF = (size_t)i * 1024 * 256;
    const size_t o256 = (size_t)i * 256, o128 = (size_t)i * 128, o1024 = (size_t)i * 1024;
    // xattn_bf already holds f2bf(mem + pos) (from conv_in or previous ln2)
    gemm_fused(xattn_bf, wbf + WE_OFF + oW, e_off_b + o256, offb,
               wbf + WE_AW + oAW, e_aw_b + o128, awb, Mrows, 256);
    gemm(mem_bf, wbf + WE_VAL + oW, e_val_b + o256, nullptr, value_bf, Mrows, 256, 256, 6);  // transposed
    deform_sample_kernel<<<cdiv_i(Mrows * NHc * 4, EB), EB, 0, stream>>>(
        encref, offb, awb, value_bf, xattn_bf, LENc, 0);  // softmax fused in-kernel
    gemm(xattn_bf, wbf + WE_OUT + oW, e_out_b + o256, bufA, nullptr, Mrows, 256, 256, 0);
    addln(mem, bufA, e_ln1_g + o256, e_ln1_b + o256, mem_bf, Mrows, nullptr, nullptr, 0);
    gemm(mem_bf, wbf + WE_F1 + oF, e_f1_b + o1024, nullptr, hid_bf, Mrows, 1024, 256, 3);
    gemm(hid_bf, wbf + WE_F2 + oF, e_f2_b + o256, bufA, nullptr, Mrows, 256, 1024, 0);
    // fused: next layer's xattn_bf = f2bf(ln2_out + pos)
    addln(mem, bufA, e_ln2_g + o256, e_ln2_b + o256, mem_bf, Mrows, pos_p, xattn_bf, 0);
  }

  // ---- batched decoder value projections (transposed: planes layer*8+h) ----
  gemm(mem_bf, wbf + WD_VAL, d_val_b, nullptr, value6_bf, Mrows, 6 * 256, 256, 6);

  // ---- decoder prep ----
  dec_init_kernel<<<cdiv_i(NQc * Cc, EB), EB, 0, stream>>>(qe_p, qpos, doutb, dout_bf, qbuf_bf);
  dec_ref_kernel<<<cdiv_i(NQc * 2, EB), EB, 0, stream>>>(qe_p, ref_w, ref_b, vr_p, drefb);

  for (int i = 0; i < Lc; ++i) {
    const size_t oW = (size_t)i * 256 * 256, oAW = (size_t)i * 128 * 256, oF = (size_t)i * 1024 * 256;
    const size_t oSA = (size_t)i * 768 * 256;
    const size_t o256 = (size_t)i * 256, o128 = (size_t)i * 128, o1024 = (size_t)i * 1024, o768 = (size_t)i * 768;
    // self-attention (qk + v fused; qbuf_bf pre-computed by dec_init / previous ln3)
    gemm_s_sa(qbuf_bf, dout_bf, wbf + WD_SAIN + oSA, d_sa_in_b + o768, qkb, dvb, Mdec, 256);
    mha_core_kernel<<<Bc * NHc * NQc / 4, 256, 0, stream>>>(qkb, dvb, dattn_bf);
    gemm_s(dattn_bf, wbf + WD_SAOUT + oW, d_sa_out_b + o256, dproj, nullptr, Mdec, 256, 256, 0);
    // fused: qbuf_bf = f2bf(ln2_out + qpos) for cross-attention
    addln(doutb, dproj, d_ln2_g + o256, d_ln2_b + o256, dout_bf, Mdec, qpos, qbuf_bf, NQc);
    // cross (deformable) attention
    gemm_s_fused(qbuf_bf, wbf + WD_OFF + oW, d_off_b + o256, doffb,
                 wbf + WD_AW + oAW, d_aw_b + o128, dawb, Mdec, 256);
    deform_sample_kernel<<<cdiv_i(Mdec * NHc * 4, EB), EB, 0, stream>>>(
        drefb, doffb, dawb, value6_bf, dattn_bf, NQc, i * 8);  // softmax fused in-kernel
    gemm_s(dattn_bf, wbf + WD_OUT + oW, d_out_b + o256, dproj, nullptr, Mdec, 256, 256, 0);
    addln(doutb, dproj, d_ln1_g + o256, d_ln1_b + o256, dout_bf, Mdec, nullptr, nullptr, 0);
    // FFN
    gemm_s(dout_bf, wbf + WD_F1 + oF, d_f1_b + o1024, nullptr, dhid_bf, Mdec, 1024, 256, 3);
    gemm_s(dhid_bf, wbf + WD_F2 + oF, d_f2_b + o256, dproj, nullptr, Mdec, 256, 1024, 0);
    // fused: qbuf_bf = f2bf(ln3_out + qpos) for next layer's self-attention
    addln(doutb, dproj, d_ln3_g + o256, d_ln3_b + o256, dout_bf, Mdec, qpos, qbuf_bf, NQc);
  }

  store_f32_kernel<<<cdiv_i(out_size / 4, EB), EB, 0, stream>>>(doutb, (float*)d_out, out_size / 4);
}

// Round 16
// 2079.985 us; speedup vs baseline: 1.0885x; 1.0885x over previous
//
#include <hip/hip_runtime.h>

#define DINLINE __device__ __forceinline__

#define Bc 2
#define LENc 13294
#define Cc 256
#define NHc 8
#define NQc 300
#define Lc 6
#define FFc 1024

typedef unsigned short u16;
typedef __attribute__((ext_vector_type(8))) short bshort8;
typedef __attribute__((ext_vector_type(8))) unsigned short ushort8v;
typedef __attribute__((ext_vector_type(4))) float f32x4;
typedef __attribute__((ext_vector_type(2))) float f32x2;

DINLINE float bf2f(u16 u) { return __uint_as_float(((unsigned)u) << 16); }
DINLINE u16 f2bf(float f) {
  unsigned u = __float_as_uint(f);
  return (u16)((u + 0x7fffu + ((u >> 16) & 1u)) >> 16);
}
// one u32 = 2 packed bf16 channels -> 2 f32 in 2 bit-ops (exact)
DINLINE f32x2 cvt2(unsigned u) {
  f32x2 r;
  r.x = __uint_as_float(u << 16);
  r.y = __uint_as_float(u & 0xffff0000u);
  return r;
}
DINLINE void glds16(const u16* g, u16* l) {
  __builtin_amdgcn_global_load_lds((const __attribute__((address_space(1))) void*)g,
                                   (__attribute__((address_space(3))) void*)l, 16, 0, 0);
}

// ============ packed f32 -> bf16 weight conversion ============
struct WPack {
  const float* src[14];
  int off4[15];
};
__global__ void convert_weights_kernel(WPack p, u16* __restrict__ dst) {
  int i4 = blockIdx.x * 256 + threadIdx.x;
  if (i4 >= p.off4[14]) return;
  int t = 0;
#pragma unroll
  for (int k = 0; k < 13; ++k) t += (i4 >= p.off4[k + 1]) ? 1 : 0;
  int local = i4 - p.off4[t];
  float4 v = *(const float4*)(p.src[t] + (size_t)local * 4);
  ushort4 o;
  o.x = f2bf(v.x); o.y = f2bf(v.y); o.z = f2bf(v.z); o.w = f2bf(v.w);
  *(ushort4*)(dst + (size_t)i4 * 4) = o;
}

// ============ MFMA GEMM 128x128, double-buffered, XCD-swizzled ============
// flags: bit0 relu, bit1 bf16 out, bit2 head-transposed bf16 out, bit3 fused off/aw
// bf16 epilogue: 1-pass 128x128 LDS stage, quad-XOR bank swizzle.
// tpose store remap: 16-lane runs walk (pix,cc) within one head plane.
__global__ __launch_bounds__(256) void gemm_mfma_kernel(
    const u16* __restrict__ X, const u16* __restrict__ W, const float* __restrict__ bias,
    float* __restrict__ Yf, u16* __restrict__ Yb, int M, int N, int K, int flags,
    const u16* __restrict__ W2, const float* __restrict__ bias2, float* __restrict__ Yf2) {
  __shared__ __align__(16) u16 lds[2][8256];
  const int tid = threadIdx.x;
  int bx = blockIdx.x, by = blockIdx.y;
  {
    const int nx = gridDim.x, ny = gridDim.y;
    if ((ny & 7) == 0) {
      int d = by * nx + bx;
      int grp = nx << 3;                 // 8 m-rows x all n per group
      int r = d % grp, q = d / grp;
      by = (r & 7) + (q << 3);
      bx = r >> 3;
    }
  }
  const int m0 = by << 7, n0 = bx << 7;
  const int w = tid >> 6, lane = tid & 63;
  const int wm = (w & 1) << 6, wn = (w >> 1) << 6;
  const int lane15 = lane & 15, quad = lane >> 4;
  const bool fus = (flags & 8) != 0;
  const bool sec = fus && (n0 >= 256);
  const u16* Wb = sec ? W2 : W;
  const int nb0 = sec ? n0 - 256 : n0;
  f32x4 acc[4][4] = {};

  int gmA0 = m0 + lane;       if (gmA0 >= M) gmA0 = M - 1;
  int gmA1 = m0 + 64 + lane;  if (gmA1 >= M) gmA1 = M - 1;
  const u16* xa0 = X + (size_t)gmA0 * K + w * 8;
  const u16* xa1 = X + (size_t)gmA1 * K + w * 8;
  const u16* wb0 = Wb + (size_t)(nb0 + lane) * K + w * 8;
  const u16* wb1 = Wb + (size_t)(nb0 + 64 + lane) * K + w * 8;
  u16* lbase = &lds[0][0];
  const int wslot = w * 1032;

  glds16(xa0, lbase + wslot);
  glds16(xa1, lbase + wslot + 512);
  glds16(wb0, lbase + 4128 + wslot);
  glds16(wb1, lbase + 4128 + wslot + 512);
  __syncthreads();

  int cur = 0;
  for (int kt = 0; kt < K; kt += 32) {
    if (kt + 32 < K) {
      u16* nb = lbase + (cur ^ 1) * 8256;
      glds16(xa0 + kt + 32, nb + wslot);
      glds16(xa1 + kt + 32, nb + wslot + 512);
      glds16(wb0 + kt + 32, nb + 4128 + wslot);
      glds16(wb1 + kt + 32, nb + 4128 + wslot + 512);
    }
    const u16* cb = lbase + cur * 8256;
    bshort8 af[4], bfr[4];
#pragma unroll
    for (int mi = 0; mi < 4; ++mi)
      af[mi] = *(const bshort8*)&cb[quad * 1032 + (wm + mi * 16 + lane15) * 8];
#pragma unroll
    for (int ni = 0; ni < 4; ++ni)
      bfr[ni] = *(const bshort8*)&cb[4128 + quad * 1032 + (wn + ni * 16 + lane15) * 8];
#pragma unroll
    for (int mi = 0; mi < 4; ++mi)
#pragma unroll
      for (int ni = 0; ni < 4; ++ni)
        acc[mi][ni] = __builtin_amdgcn_mfma_f32_16x16x32_bf16(af[mi], bfr[ni], acc[mi][ni], 0, 0, 0);
    __syncthreads();
    cur ^= 1;
  }

  float bv[4];
#pragma unroll
  for (int ni = 0; ni < 4; ++ni) {
    int nc = nb0 + wn + ni * 16 + lane15;
    bv[ni] = sec ? bias2[nc] : bias[nc];
  }
  const int relu = flags & 1, asbf = flags & 2, tpose = flags & 4;
  const int ldy = fus ? 256 : N;

  if (asbf | tpose) {
    // ---- 1-pass LDS-staged coalesced bf16 epilogue, quad-XOR bank swizzle ----
    u16* eb = &lds[0][0];  // 128*128 = 16384 u16 <= 16512
#pragma unroll
    for (int mi = 0; mi < 4; ++mi)
#pragma unroll
      for (int reg = 0; reg < 4; ++reg) {
        int row = wm + mi * 16 + quad * 4 + reg;   // (row>>2)&3 == quad
#pragma unroll
        for (int ni = 0; ni < 4; ++ni) {
          float v = acc[mi][ni][reg] + bv[ni];
          if (relu) v = fmaxf(v, 0.f);
          int col = (wn + ni * 16 + lane15) ^ (quad << 4);
          eb[row * 128 + col] = f2bf(v);
        }
      }
    __syncthreads();
    if (tpose) {
      // 16-lane run covers 4 consecutive pix x 4 cc-chunks within ONE head plane.
      const int cc8 = (tid & 3) * 8;        // channel chunk 0,8,16,24
      const int pix4 = (tid >> 2) & 3;      // 4 consecutive rows
      const int hgi = (tid >> 4) & 3;       // head plane within the 128-col tile
#pragma unroll
      for (int pass = 0; pass < 8; ++pass) {
        int row = pass * 16 + (tid >> 6) * 4 + pix4;
        int s = (row >> 2) & 3;
        int gm = m0 + row;
        int col = hgi * 32 + cc8;
        ushort8v v = *(const ushort8v*)&eb[row * 128 + (col ^ (s << 4))];
        if (gm < M) {
          int gc = n0 + col;
          int hg = gc >> 5;
          int bb = gm / LENc, pix = gm - bb * LENc;
          *(ushort8v*)&Yb[(((size_t)hg * Bc + bb) * LENc + pix) * 32 + cc8] = v;
        }
      }
    } else {
      const int r4 = tid >> 4, cg = tid & 15;
#pragma unroll
      for (int pass = 0; pass < 8; ++pass) {
        int row = pass * 16 + r4;
        int s = (row >> 2) & 3;
        int gm = m0 + row;
        ushort8v v = *(const ushort8v*)&eb[row * 128 + ((cg * 8) ^ (s << 4))];
        if (gm < M) {
          *(ushort8v*)&Yb[(size_t)gm * ldy + n0 + cg * 8] = v;
        }
      }
    }
    return;
  }

#pragma unroll
  for (int mi = 0; mi < 4; ++mi)
#pragma unroll
    for (int reg = 0; reg < 4; ++reg) {
      int gm = m0 + wm + mi * 16 + quad * 4 + reg;
      if (gm >= M) continue;
#pragma unroll
      for (int ni = 0; ni < 4; ++ni) {
        float v = acc[mi][ni][reg] + bv[ni];
        if (relu) v = fmaxf(v, 0.f);
        int gc = nb0 + wn + ni * 16 + lane15;
        if (sec) Yf2[(size_t)gm * 128 + gc] = v;
        else Yf[(size_t)gm * ldy + gc] = v;
      }
    }
}

// ============ MFMA GEMM 64x64 (small M, decoder), double-buffered ============
// flags: bit0 relu, bit1 bf16 out, bit3 fused off/aw (sec=n0>=256, out stride 128),
//        bit4 fused sa qk+v (sec=n0>=512, X2/dout input, out stride 256)
__global__ __launch_bounds__(256) void gemm_small_kernel(
    const u16* __restrict__ X, const u16* __restrict__ W, const float* __restrict__ bias,
    float* __restrict__ Yf, u16* __restrict__ Yb, int M, int N, int K, int flags,
    const u16* __restrict__ W2, const float* __restrict__ bias2, float* __restrict__ Yf2,
    const u16* __restrict__ X2) {
  __shared__ __align__(16) u16 lds[2][4160];
  const int tid = threadIdx.x;
  const int m0 = blockIdx.y << 6, n0 = blockIdx.x << 6;
  const int w = tid >> 6, lane = tid & 63;
  const int wm = (w & 1) << 5, wn = (w >> 1) << 5;
  const int lane15 = lane & 15, quad = lane >> 4;
  const bool fus3 = (flags & 8) != 0;
  const bool fus4 = (flags & 16) != 0;
  const bool sec = (fus3 && n0 >= 256) || (fus4 && n0 >= 512);
  const int secbase = fus4 ? 512 : 256;
  const u16* Wb = sec ? W2 : W;
  const u16* Xs = (sec && fus4) ? X2 : X;
  const int nb0 = sec ? n0 - secbase : n0;
  const int ldy1 = fus3 ? 256 : (fus4 ? 512 : N);
  const int ldy2 = fus4 ? 256 : 128;
  f32x4 acc[2][2] = {};

  int gmA = m0 + lane; if (gmA >= M) gmA = M - 1;
  const u16* xa = Xs + (size_t)gmA * K + w * 8;
  const u16* wb = Wb + (size_t)(nb0 + lane) * K + w * 8;
  u16* lbase = &lds[0][0];
  const int wslot = w * 520;

  glds16(xa, lbase + wslot);
  glds16(wb, lbase + 2080 + wslot);
  __syncthreads();

  int cur = 0;
  for (int kt = 0; kt < K; kt += 32) {
    if (kt + 32 < K) {
      u16* nb = lbase + (cur ^ 1) * 4160;
      glds16(xa + kt + 32, nb + wslot);
      glds16(wb + kt + 32, nb + 2080 + wslot);
    }
    const u16* cb = lbase + cur * 4160;
    bshort8 af[2], bfr[2];
#pragma unroll
    for (int mi = 0; mi < 2; ++mi)
      af[mi] = *(const bshort8*)&cb[quad * 520 + (wm + mi * 16 + lane15) * 8];
#pragma unroll
    for (int ni = 0; ni < 2; ++ni)
      bfr[ni] = *(const bshort8*)&cb[2080 + quad * 520 + (wn + ni * 16 + lane15) * 8];
#pragma unroll
    for (int mi = 0; mi < 2; ++mi)
#pragma unroll
      for (int ni = 0; ni < 2; ++ni)
        acc[mi][ni] = __builtin_amdgcn_mfma_f32_16x16x32_bf16(af[mi], bfr[ni], acc[mi][ni], 0, 0, 0);
    __syncthreads();
    cur ^= 1;
  }

  float bv[2];
#pragma unroll
  for (int ni = 0; ni < 2; ++ni) {
    int nc = nb0 + wn + ni * 16 + lane15;
    bv[ni] = sec ? bias2[nc] : bias[nc];
  }
  const int relu = flags & 1, asbf = flags & 2;
#pragma unroll
  for (int mi = 0; mi < 2; ++mi)
#pragma unroll
    for (int reg = 0; reg < 4; ++reg) {
      int gm = m0 + wm + mi * 16 + quad * 4 + reg;
      if (gm >= M) continue;
#pragma unroll
      for (int ni = 0; ni < 2; ++ni) {
        float v = acc[mi][ni][reg] + bv[ni];
        if (relu) v = fmaxf(v, 0.f);
        int gc = nb0 + wn + ni * 16 + lane15;
        if (sec) Yf2[(size_t)gm * ldy2 + gc] = v;
        else if (asbf) Yb[(size_t)gm * ldy1 + gc] = f2bf(v);
        else Yf[(size_t)gm * ldy1 + gc] = v;
      }
    }
}

// ============ elementwise (float4) ============
// conv_in: mem=src (f32), mem_bf=f2bf(src), xattn=f2bf(src+pos)  (layer-0 input)
__global__ void conv_in_kernel(const float* __restrict__ in, const float* __restrict__ pos,
                               float* __restrict__ outf, u16* __restrict__ outb,
                               u16* __restrict__ xat, int n4) {
  int i = blockIdx.x * 256 + threadIdx.x;
  if (i >= n4) return;
  float4 v = *(const float4*)(in + (size_t)i * 4);
  float4 p = *(const float4*)(pos + (size_t)i * 4);
  *(float4*)(outf + (size_t)i * 4) = v;
  ushort4 o; o.x = f2bf(v.x); o.y = f2bf(v.y); o.z = f2bf(v.z); o.w = f2bf(v.w);
  *(ushort4*)(outb + (size_t)i * 4) = o;
  ushort4 x; x.x = f2bf(v.x + p.x); x.y = f2bf(v.y + p.y);
  x.z = f2bf(v.z + p.z); x.w = f2bf(v.w + p.w);
  *(ushort4*)(xat + (size_t)i * 4) = x;
}
__global__ void store_f32_kernel(const float* __restrict__ in, float* __restrict__ out, int n4) {
  int i = blockIdx.x * 256 + threadIdx.x;
  if (i < n4) *(float4*)(out + (size_t)i * 4) = *(const float4*)(in + (size_t)i * 4);
}

// ============ residual + LN: wave per row, float4, shfl-only ============
// Optional fused epilogue: if extra != nullptr, also writes
//   extra[row*256+c] = f2bf(y + addv[prow*256+c]) with prow = wrap ? row%wrap : row.
__global__ __launch_bounds__(256) void add_ln_kernel(
    float* __restrict__ res, const float* __restrict__ x,
    const float* __restrict__ g, const float* __restrict__ b,
    u16* __restrict__ shadow, int M,
    const float* __restrict__ addv, u16* __restrict__ extra, int wrap) {
  int row = blockIdx.x * 4 + (threadIdx.x >> 6);
  int lane = threadIdx.x & 63;
  if (row >= M) return;
  size_t base = (size_t)row * 256 + lane * 4;
  float4 rv = *(const float4*)(res + base);
  float4 xv = *(const float4*)(x + base);
  float v0 = rv.x + xv.x, v1 = rv.y + xv.y, v2 = rv.z + xv.z, v3 = rv.w + xv.w;
  float s = v0 + v1 + v2 + v3;
#pragma unroll
  for (int o = 32; o > 0; o >>= 1) s += __shfl_xor(s, o, 64);
  float mean = s * (1.f / 256.f);
  float d0 = v0 - mean, d1 = v1 - mean, d2 = v2 - mean, d3 = v3 - mean;
  float s2 = d0 * d0 + d1 * d1 + d2 * d2 + d3 * d3;
#pragma unroll
  for (int o = 32; o > 0; o >>= 1) s2 += __shfl_xor(s2, o, 64);
  float rstd = rsqrtf(s2 * (1.f / 256.f) + 1e-5f);
  float4 gv = *(const float4*)(g + lane * 4);
  float4 bv = *(const float4*)(b + lane * 4);
  float y0 = d0 * rstd * gv.x + bv.x;
  float y1 = d1 * rstd * gv.y + bv.y;
  float y2 = d2 * rstd * gv.z + bv.z;
  float y3 = d3 * rstd * gv.w + bv.w;
  float4 yo; yo.x = y0; yo.y = y1; yo.z = y2; yo.w = y3;
  *(float4*)(res + base) = yo;
  ushort4 so; so.x = f2bf(y0); so.y = f2bf(y1); so.z = f2bf(y2); so.w = f2bf(y3);
  *(ushort4*)(shadow + base) = so;
  if (extra) {
    int prow = wrap ? (row % wrap) : row;
    float4 pv = *(const float4*)(addv + (size_t)prow * 256 + lane * 4);
    ushort4 eo;
    eo.x = f2bf(y0 + pv.x); eo.y = f2bf(y1 + pv.y);
    eo.z = f2bf(y2 + pv.z); eo.w = f2bf(y3 + pv.w);
    *(ushort4*)(extra + base) = eo;
  }
}

__global__ void enc_ref_kernel(const float* __restrict__ vr, float* __restrict__ ref) {
  int idx = blockIdx.x * 256 + threadIdx.x;
  if (idx >= Bc * LENc) return;
  int b = idx / LENc, p = idx % LENc;
  int st, HW, lvl;
  if (p < 10000)      { lvl = 0; st = 0;     HW = 100; }
  else if (p < 12500) { lvl = 1; st = 10000; HW = 50; }
  else if (p < 13125) { lvl = 2; st = 12500; HW = 25; }
  else                { lvl = 3; st = 13125; HW = 13; }
  int r = p - st;
  int i = r / HW, j = r % HW;
  float vrx = vr[(b * 4 + lvl) * 2 + 0];
  float vry = vr[(b * 4 + lvl) * 2 + 1];
  float ry = (i + 0.5f) / (vry * HW);
  float rx = (j + 0.5f) / (vrx * HW);
#pragma unroll
  for (int l = 0; l < 4; ++l) {
    ref[((size_t)idx * 4 + l) * 2 + 0] = rx * vr[(b * 4 + l) * 2 + 0];
    ref[((size_t)idx * 4 + l) * 2 + 1] = ry * vr[(b * 4 + l) * 2 + 1];
  }
}

__global__ void dec_ref_kernel(const float* __restrict__ qe, const float* __restrict__ rw,
                               const float* __restrict__ rb, const float* __restrict__ vr,
                               float* __restrict__ dref) {
  int idx = blockIdx.x * 256 + threadIdx.x;
  if (idx >= NQc * 2) return;
  int qi = idx >> 1, c = idx & 1;
  float s = rb[c];
  for (int k = 0; k < 256; ++k)
    s += qe[(size_t)qi * 512 + k] * rw[c * 256 + k];
  s = 1.f / (1.f + expf(-s));
  for (int b = 0; b < Bc; ++b)
#pragma unroll
    for (int l = 0; l < 4; ++l)
      dref[(((size_t)(b * NQc + qi)) * 4 + l) * 2 + c] = s * vr[(b * 4 + l) * 2 + c];
}

// dec_init: qpos, dout (both batches), dout_bf, and qbuf_bf = f2bf(tgt + qpos)
__global__ void dec_init_kernel(const float* __restrict__ qe, float* __restrict__ qpos,
                                float* __restrict__ outf, u16* __restrict__ outb,
                                u16* __restrict__ qbuf) {
  int i = blockIdx.x * 256 + threadIdx.x;
  if (i >= NQc * Cc) return;
  int qi = i >> 8, c = i & 255;
  float qp = qe[(size_t)qi * 512 + c];
  qpos[i] = qp;
  float t = qe[(size_t)qi * 512 + 256 + c];
  outf[i] = t;
  outf[NQc * Cc + i] = t;
  u16 tb = f2bf(t);
  outb[i] = tb;
  outb[NQc * Cc + i] = tb;
  u16 qb = f2bf(t + qp);
  qbuf[i] = qb;
  qbuf[NQc * Cc + i] = qb;
}

// ============ deformable sampler v5: fused softmax + tap-parallel + shfl broadcast ======
// aw holds RAW LOGITS; softmax over the 16 (l,p) entries computed in-kernel.
__global__ __launch_bounds__(256) void deform_sample_kernel(
    const float* __restrict__ ref, const float* __restrict__ off,
    const float* __restrict__ aw, const u16* __restrict__ value_t,
    u16* __restrict__ out, int Q, int plane_base) {
  __shared__ float sOff[2048];  // 8 bq x (8 h x 32), idx ^= h*4
  __shared__ float sAw[1024];   // 8 bq x (8 h x 16), idx ^= (h>>1)*4
  __shared__ float sRef[64];    // 8 bq x 8
  const int t = threadIdx.x;
  const int bq0 = blockIdx.x * 8;
  const int nbq = Bc * Q;
#pragma unroll
  for (int it = 0; it < 2; ++it) {
    int e = (it * 256 + t) * 4;          // float idx: bqL*256 + h*32 + k
    int bqL = e >> 8;
    int hh = (e >> 5) & 7;
    int sbq = bq0 + bqL; if (sbq >= nbq) sbq = nbq - 1;
    float4 v = *(const float4*)(off + (size_t)sbq * 256 + (e & 255));
    *(float4*)&sOff[e ^ (hh << 2)] = v;
  }
  {
    int e = t * 4;                       // float idx: bqL*128 + h*16 + j
    int bqL = e >> 7;
    int hh = (e >> 4) & 7;
    int sbq = bq0 + bqL; if (sbq >= nbq) sbq = nbq - 1;
    float4 v = *(const float4*)(aw + (size_t)sbq * 128 + (e & 127));
    *(float4*)&sAw[e ^ ((hh >> 1) << 2)] = v;
  }
  if (t < 16) {
    int bqL = t >> 1;
    int sbq = bq0 + bqL; if (sbq >= nbq) sbq = nbq - 1;
    float4 v = *(const float4*)(ref + (size_t)sbq * 8 + (t & 1) * 4);
    *(float4*)&sRef[t * 4] = v;
  }
  __syncthreads();
  const int c8 = t & 3;
  const int h = (t >> 2) & 7;
  const int bqL = t >> 5;
  const int bq = bq0 + bqL;
  if (bq >= nbq) return;
  const int b = bq / Q;
  const int HWs[4] = {100, 50, 25, 13};
  const int starts[4] = {0, 10000, 12500, 13125};
  const float* sOb = &sOff[(bqL << 8) + (h << 5)];
  const float* sAb = &sAw[(bqL << 7) + (h << 4)];
  const float* sRb = &sRef[bqL << 3];
  const int hswo = h << 2;
  const int hswa = (h >> 1) << 2;
  const u16* vplane = value_t + ((size_t)(plane_base + h) * Bc + b) * LENc * 32 + c8 * 8;

  // ---- fused softmax over the unit's 16 logits (4 per lane x 4-lane group) ----
  float lg[4];
#pragma unroll
  for (int l = 0; l < 4; ++l) lg[l] = sAb[(l * 4 + c8) ^ hswa];
  float mx = fmaxf(fmaxf(lg[0], lg[1]), fmaxf(lg[2], lg[3]));
  mx = fmaxf(mx, __shfl_xor(mx, 1, 64));
  mx = fmaxf(mx, __shfl_xor(mx, 2, 64));
  float ew[4];
  float ssum = 0.f;
#pragma unroll
  for (int l = 0; l < 4; ++l) { ew[l] = expf(lg[l] - mx); ssum += ew[l]; }
  ssum += __shfl_xor(ssum, 1, 64);
  ssum += __shfl_xor(ssum, 2, 64);
  const float sinv = 1.f / ssum;

  // ---- Phase A: this lane computes tap (l, p=c8) for l=0..3 ----
  float tw00[4], tw10[4], tw01[4], tw11[4];
  int tp00[4], tp10[4], tp01[4], tp11[4];
#pragma unroll
  for (int l = 0; l < 4; ++l) {
    const int HW = HWs[l];
    const float HWf = (float)HW;
    const int st = starts[l];
    const int p = c8;
    float rx = sRb[l * 2 + 0], ry = sRb[l * 2 + 1];
    float ox = sOb[((l * 4 + p) * 2 + 0) ^ hswo];
    float oy = sOb[((l * 4 + p) * 2 + 1) ^ hswo];
    float wgt = ew[l] * sinv;
    float x = rx * HWf + ox - 0.5f;
    float y = ry * HWf + oy - 0.5f;
    float xf = floorf(x), yf = floorf(y);
    float wx = x - xf, wy = y - yf;
    int x0 = (int)xf, y0 = (int)yf;
    bool vx0 = ((unsigned)x0 < (unsigned)HW);
    bool vx1 = ((unsigned)(x0 + 1) < (unsigned)HW);
    bool vy0 = ((unsigned)y0 < (unsigned)HW);
    bool vy1 = ((unsigned)(y0 + 1) < (unsigned)HW);
    int xc0 = min(max(x0, 0), HW - 1);
    int xc1 = min(max(x0 + 1, 0), HW - 1);
    int yc0 = min(max(y0, 0), HW - 1);
    int yc1 = min(max(y0 + 1, 0), HW - 1);
    tw00[l] = (vx0 & vy0) ? (1.f - wx) * (1.f - wy) * wgt : 0.f;
    tw10[l] = (vx1 & vy0) ? wx * (1.f - wy) * wgt : 0.f;
    tw01[l] = (vx0 & vy1) ? (1.f - wx) * wy * wgt : 0.f;
    tw11[l] = (vx1 & vy1) ? wx * wy * wgt : 0.f;
    int r0 = (st + yc0 * HW) << 5;
    int r1 = (st + yc1 * HW) << 5;
    tp00[l] = r0 + (xc0 << 5);
    tp10[l] = r0 + (xc1 << 5);
    tp01[l] = r1 + (xc0 << 5);
    tp11[l] = r1 + (xc1 << 5);
  }

  // ---- Phase B: gather + accumulate; tap data broadcast from lane (base|p) ----
  const int lnbase = t & ~3;  // within-wave group base (shfl uses block-lane id mod 64)
  f32x2 a2[4] = {};
#pragma unroll
  for (int l = 0; l < 4; ++l) {
#pragma unroll
    for (int p = 0; p < 4; ++p) {
      const int src = lnbase + p;
      float w00 = __shfl(tw00[l], src, 64);
      float w10 = __shfl(tw10[l], src, 64);
      float w01 = __shfl(tw01[l], src, 64);
      float w11 = __shfl(tw11[l], src, 64);
      int p00 = __shfl(tp00[l], src, 64);
      int p10 = __shfl(tp10[l], src, 64);
      int p01 = __shfl(tp01[l], src, 64);
      int p11 = __shfl(tp11[l], src, 64);
      const uint4 q00 = *(const uint4*)(vplane + p00);
      const uint4 q10 = *(const uint4*)(vplane + p10);
      const uint4 q01 = *(const uint4*)(vplane + p01);
      const uint4 q11 = *(const uint4*)(vplane + p11);
      f32x2 w002 = {w00, w00}, w102 = {w10, w10}, w012 = {w01, w01}, w112 = {w11, w11};
      a2[0] += w002 * cvt2(q00.x) + w102 * cvt2(q10.x) + w012 * cvt2(q01.x) + w112 * cvt2(q11.x);
      a2[1] += w002 * cvt2(q00.y) + w102 * cvt2(q10.y) + w012 * cvt2(q01.y) + w112 * cvt2(q11.y);
      a2[2] += w002 * cvt2(q00.z) + w102 * cvt2(q10.z) + w012 * cvt2(q01.z) + w112 * cvt2(q11.z);
      a2[3] += w002 * cvt2(q00.w) + w102 * cvt2(q10.w) + w012 * cvt2(q01.w) + w112 * cvt2(q11.w);
    }
  }
  ushort8v o;
#pragma unroll
  for (int j = 0; j < 4; ++j) {
    o[2 * j] = f2bf(a2[j].x);
    o[2 * j + 1] = f2bf(a2[j].y);
  }
  *(ushort8v*)(out + (size_t)bq * 256 + h * 32 + c8 * 8) = o;
}

// ============ decoder self-attention core v2: block-shared K/V in LDS ============
// 4 waves per block = 4 consecutive qi of the SAME (b,h) (300 % 4 == 0 -> exact).
// Stage K^T (stride 301, conflict-free d-major reads) -> QK from LDS;
// barrier; restage V (stride 33, conflict-free) -> PV from LDS (2-way j-split).
__global__ __launch_bounds__(256) void mha_core_kernel(
    const float* __restrict__ qk, const float* __restrict__ v, u16* __restrict__ out) {
  __shared__ float sc[4][304];
  __shared__ float buf[9900];   // union: K^T (32 x stride 301) then V (300 x stride 33)
  const int tid = threadIdx.x;
  const int wslot = tid >> 6;
  const int lane = tid & 63;
  const int g = blockIdx.x / 75;           // 75 blocks per (b,h)
  const int b = g >> 3;
  const int h = g & 7;
  const int qi = (blockIdx.x % 75) * 4 + wslot;
  const float scale = 0.1767766952966369f;

  // ---- stage K^T: buf[d*301 + j] ----
  for (int idx = tid; idx < NQc * 8; idx += 256) {
    int row = idx >> 3, chunk = idx & 7;
    float4 kv = *(const float4*)(qk + ((size_t)(b * NQc + row)) * 512 + 256 + h * 32 + chunk * 4);
    int d0 = chunk * 4;
    buf[(d0 + 0) * 301 + row] = kv.x;
    buf[(d0 + 1) * 301 + row] = kv.y;
    buf[(d0 + 2) * 301 + row] = kv.z;
    buf[(d0 + 3) * 301 + row] = kv.w;
  }
  float qv[32];
  const float* qptr = qk + ((size_t)(b * NQc + qi)) * 512 + h * 32;
#pragma unroll
  for (int d = 0; d < 32; ++d) qv[d] = qptr[d];
  __syncthreads();

  // ---- QK from LDS ----
  float mx = -1e30f;
  for (int j = lane; j < NQc; j += 64) {
    float s = 0.f;
#pragma unroll
    for (int d = 0; d < 32; ++d) s += qv[d] * buf[d * 301 + j];
    s *= scale;
    sc[wslot][j] = s;
    mx = fmaxf(mx, s);
  }
#pragma unroll
  for (int o = 32; o > 0; o >>= 1) mx = fmaxf(mx, __shfl_xor(mx, o, 64));
  float se = 0.f;
  for (int j = lane; j < NQc; j += 64) {
    float e = expf(sc[wslot][j] - mx);
    sc[wslot][j] = e;
    se += e;
  }
#pragma unroll
  for (int o = 32; o > 0; o >>= 1) se += __shfl_xor(se, o, 64);
  float inv = 1.f / se;
  __syncthreads();   // all waves done reading K^T before V overwrites buf

  // ---- stage V: buf[row*33 + d] ----
  for (int idx = tid; idx < NQc * 8; idx += 256) {
    int row = idx >> 3, chunk = idx & 7;
    float4 vv = *(const float4*)(v + ((size_t)(b * NQc + row)) * 256 + h * 32 + chunk * 4);
    int base = row * 33 + chunk * 4;
    buf[base + 0] = vv.x; buf[base + 1] = vv.y;
    buf[base + 2] = vv.z; buf[base + 3] = vv.w;
  }
  __syncthreads();

  // ---- PV from LDS: halves split even/odd j, combine with xor-32 ----
  const int half = lane >> 5;
  const int d = lane & 31;
  float acc = 0.f;
  for (int j = half; j < NQc; j += 2)
    acc += sc[wslot][j] * buf[j * 33 + d];
  acc += __shfl_xor(acc, 32, 64);
  if (lane < 32)
    out[((size_t)(b * NQc + qi)) * 256 + h * 32 + d] = f2bf(acc * inv);
}

// ============ host ============
static inline int cdiv_i(int a, int b) { return (a + b - 1) / b; }

#define WE_OFF   0
#define WE_AW    393216
#define WE_VAL   589824
#define WE_OUT   983040
#define WE_F1    1376256
#define WE_F2    2949120
#define WD_SAIN  4521984
#define WD_SAOUT 5701632
#define WD_OFF   6094848
#define WD_AW    6488064
#define WD_VAL   6684672
#define WD_OUT   7077888
#define WD_F1    7471104
#define WD_F2    9043968
#define W_TOTAL  10616832

extern "C" void kernel_launch(void* const* d_in, const int* in_sizes, int n_in,
                              void* d_out, int out_size, void* d_ws, size_t ws_size,
                              hipStream_t stream) {
  (void)in_sizes; (void)n_in;
  const float* src_p = (const float*)d_in[0];
  const float* pos_p = (const float*)d_in[1];
  const float* qe_p = (const float*)d_in[2];
  const float* vr_p = (const float*)d_in[3];
  const float* e_off_w = (const float*)d_in[4];  const float* e_off_b = (const float*)d_in[5];
  const float* e_aw_w = (const float*)d_in[6];   const float* e_aw_b = (const float*)d_in[7];
  const float* e_val_w = (const float*)d_in[8];  const float* e_val_b = (const float*)d_in[9];
  const float* e_out_w = (const float*)d_in[10]; const float* e_out_b = (const float*)d_in[11];
  const float* e_f1_w = (const float*)d_in[12];  const float* e_f1_b = (const float*)d_in[13];
  const float* e_f2_w = (const float*)d_in[14];  const float* e_f2_b = (const float*)d_in[15];
  const float* d_sa_in_w = (const float*)d_in[16];  const float* d_sa_in_b = (const float*)d_in[17];
  const float* d_sa_out_w = (const float*)d_in[18]; const float* d_sa_out_b = (const float*)d_in[19];
  const float* d_off_w = (const float*)d_in[20]; const float* d_off_b = (const float*)d_in[21];
  const float* d_aw_w = (const float*)d_in[22];  const float* d_aw_b = (const float*)d_in[23];
  const float* d_val_w = (const float*)d_in[24]; const float* d_val_b = (const float*)d_in[25];
  const float* d_out_w = (const float*)d_in[26]; const float* d_out_b = (const float*)d_in[27];
  const float* d_f1_w = (const float*)d_in[28];  const float* d_f1_b = (const float*)d_in[29];
  const float* d_f2_w = (const float*)d_in[30];  const float* d_f2_b = (const float*)d_in[31];
  const float* ref_w = (const float*)d_in[32];   const float* ref_b = (const float*)d_in[33];
  const float* e_ln1_g = (const float*)d_in[34]; const float* e_ln1_b = (const float*)d_in[35];
  const float* e_ln2_g = (const float*)d_in[36]; const float* e_ln2_b = (const float*)d_in[37];
  const float* d_ln1_g = (const float*)d_in[38]; const float* d_ln1_b = (const float*)d_in[39];
  const float* d_ln2_g = (const float*)d_in[40]; const float* d_ln2_b = (const float*)d_in[41];
  const float* d_ln3_g = (const float*)d_in[42]; const float* d_ln3_b = (const float*)d_in[43];

  const size_t BLC = (size_t)Bc * LENc * Cc;
  float* ws = (float*)d_ws;

  float* mem = ws;                       // BLC (dead after encoder+value6)
  float* bufA = mem + BLC;               // BLC
  float* U = bufA + BLC;                 // 2.5*BLC
  float* encref = U + (5 * BLC / 2);
  float* qpos = encref + (size_t)Bc * LENc * 8;
  float* doutb = qpos + (size_t)NQc * Cc;
  float* qkb = doutb + (size_t)Bc * NQc * Cc;
  float* dvb = qkb + (size_t)Bc * NQc * 512;
  float* drefb = dvb + (size_t)Bc * NQc * Cc;
  float* doffb = drefb + (size_t)Bc * NQc * 8;
  float* dawb = doffb + (size_t)Bc * NQc * Cc;
  float* dproj = dawb + (size_t)Bc * NQc * 128;
  float* after = dproj + (size_t)Bc * NQc * Cc;
  u16* mem_bf = (u16*)after;
  u16* qbuf_bf = mem_bf + BLC;
  u16* dout_bf = qbuf_bf + (size_t)Bc * NQc * Cc;
  u16* dattn_bf = dout_bf + (size_t)Bc * NQc * Cc;
  u16* dhid_bf = dattn_bf + (size_t)Bc * NQc * Cc;
  u16* wbf = dhid_bf + (size_t)Bc * NQc * FFc;
  u16* bf_end = wbf + W_TOTAL;
  // encoder-phase union members (in U)
  float* offb = U;
  float* awb = U + BLC;
  u16* value_bf = (u16*)(U + 3 * BLC / 2);
  u16* xattn_bf = (u16*)(U + 2 * BLC);
  u16* hid_bf = (u16*)U;
  // decoder-phase: batched value projections in dead encoder region
  u16* value6_bf = (u16*)ws;

  size_t total_bytes = (size_t)((char*)bf_end - (char*)d_ws);
  if (ws_size < total_bytes) return;

  const int Mrows = Bc * LENc;  // 26588
  const int Mdec = Bc * NQc;    // 600
  const int EB = 256;

  WPack wp;
  wp.src[0] = e_off_w;   wp.src[1] = e_aw_w;    wp.src[2] = e_val_w;  wp.src[3] = e_out_w;
  wp.src[4] = e_f1_w;    wp.src[5] = e_f2_w;    wp.src[6] = d_sa_in_w; wp.src[7] = d_sa_out_w;
  wp.src[8] = d_off_w;   wp.src[9] = d_aw_w;    wp.src[10] = d_val_w; wp.src[11] = d_out_w;
  wp.src[12] = d_f1_w;   wp.src[13] = d_f2_w;
  const int offs[15] = {WE_OFF, WE_AW, WE_VAL, WE_OUT, WE_F1, WE_F2, WD_SAIN, WD_SAOUT,
                        WD_OFF, WD_AW, WD_VAL, WD_OUT, WD_F1, WD_F2, W_TOTAL};
  for (int k = 0; k < 15; ++k) wp.off4[k] = offs[k] / 4;
  convert_weights_kernel<<<cdiv_i(W_TOTAL / 4, EB), EB, 0, stream>>>(wp, wbf);

  auto gemm = [&](const u16* Xp, const u16* Wp, const float* bp, float* Yf, u16* Yb,
                  int M, int N, int K, int flags) {
    dim3 g(N / 128, cdiv_i(M, 128));
    gemm_mfma_kernel<<<g, dim3(256), 0, stream>>>(Xp, Wp, bp, Yf, Yb, M, N, K, flags,
                                                  nullptr, nullptr, nullptr);
  };
  auto gemm_fused = [&](const u16* Xp, const u16* Wp, const float* bp, float* Yf,
                        const u16* W2p, const float* b2p, float* Yf2, int M, int K) {
    dim3 g(3, cdiv_i(M, 128));  // N = 384
    gemm_mfma_kernel<<<g, dim3(256), 0, stream>>>(Xp, Wp, bp, Yf, nullptr, M, 384, K, 8,
                                                  W2p, b2p, Yf2);
  };
  auto gemm_s = [&](const u16* Xp, const u16* Wp, const float* bp, float* Yf, u16* Yb,
                    int M, int N, int K, int flags) {
    dim3 g(N / 64, cdiv_i(M, 64));
    gemm_small_kernel<<<g, dim3(256), 0, stream>>>(Xp, Wp, bp, Yf, Yb, M, N, K, flags,
                                                   nullptr, nullptr, nullptr, nullptr);
  };
  auto gemm_s_fused = [&](const u16* Xp, const u16* Wp, const float* bp, float* Yf,
                          const u16* W2p, const float* b2p, float* Yf2, int M, int K) {
    dim3 g(6, cdiv_i(M, 64));  // N = 384
    gemm_small_kernel<<<g, dim3(256), 0, stream>>>(Xp, Wp, bp, Yf, nullptr, M, 384, K, 8,
                                                   W2p, b2p, Yf2, nullptr);
  };
  auto gemm_s_sa = [&](const u16* Xq, const u16* Xv, const u16* Wp, const float* bp,
                       float* Yqk, float* Yv, int M, int K) {
    dim3 g(12, cdiv_i(M, 64));  // N = 768: cols 0..511 -> qk (X=Xq), 512..767 -> v (X2=Xv)
    gemm_small_kernel<<<g, dim3(256), 0, stream>>>(Xq, Wp, bp, Yqk, nullptr, M, 768, K, 16,
                                                   Wp + (size_t)512 * 256, bp + 512, Yv, Xv);
  };
  auto addln = [&](float* resp, const float* xp, const float* gp, const float* bbp,
                   u16* shp, int M, const float* addv, u16* extra, int wrap) {
    add_ln_kernel<<<cdiv_i(M, 4), dim3(256), 0, stream>>>(resp, xp, gp, bbp, shp, M,
                                                          addv, extra, wrap);
  };

  conv_in_kernel<<<cdiv_i((int)(BLC / 4), EB), EB, 0, stream>>>(
      src_p, pos_p, mem, mem_bf, xattn_bf, (int)(BLC / 4));
  enc_ref_kernel<<<cdiv_i(Bc * LENc, EB), EB, 0, stream>>>(vr_p, encref);

  // ---- encoder ----
  for (int i = 0; i < Lc; ++i) {
    const size_t oW = (size_t)i * 256 * 256, oAW = (size_t)i * 128 * 256, oF = (size_t)i * 1024 * 256;
    const size_t o256 = (size_t)i * 256, o128 = (size_t)i * 128, o1024 = (size_t)i * 1024;
    // xattn_bf already holds f2bf(mem + pos) (from conv_in or previous ln2)
    gemm_fused(xattn_bf, wbf + WE_OFF + oW, e_off_b + o256, offb,
               wbf + WE_AW + oAW, e_aw_b + o128, awb, Mrows, 256);
    gemm(mem_bf, wbf + WE_VAL + oW, e_val_b + o256, nullptr, value_bf, Mrows, 256, 256, 6);  // transposed
    deform_sample_kernel<<<cdiv_i(Mrows * NHc * 4, EB), EB, 0, stream>>>(
        encref, offb, awb, value_bf, xattn_bf, LENc, 0);  // softmax fused in-kernel
    gemm(xattn_bf, wbf + WE_OUT + oW, e_out_b + o256, bufA, nullptr, Mrows, 256, 256, 0);
    addln(mem, bufA, e_ln1_g + o256, e_ln1_b + o256, mem_bf, Mrows, nullptr, nullptr, 0);
    gemm(mem_bf, wbf + WE_F1 + oF, e_f1_b + o1024, nullptr, hid_bf, Mrows, 1024, 256, 3);
    gemm(hid_bf, wbf + WE_F2 + oF, e_f2_b + o256, bufA, nullptr, Mrows, 256, 1024, 0);
    // fused: next layer's xattn_bf = f2bf(ln2_out + pos)
    addln(mem, bufA, e_ln2_g + o256, e_ln2_b + o256, mem_bf, Mrows, pos_p, xattn_bf, 0);
  }

  // ---- batched decoder value projections (transposed: planes layer*8+h) ----
  gemm(mem_bf, wbf + WD_VAL, d_val_b, nullptr, value6_bf, Mrows, 6 * 256, 256, 6);

  // ---- decoder prep ----
  dec_init_kernel<<<cdiv_i(NQc * Cc, EB), EB, 0, stream>>>(qe_p, qpos, doutb, dout_bf, qbuf_bf);
  dec_ref_kernel<<<cdiv_i(NQc * 2, EB), EB, 0, stream>>>(qe_p, ref_w, ref_b, vr_p, drefb);

  for (int i = 0; i < Lc; ++i) {
    const size_t oW = (size_t)i * 256 * 256, oAW = (size_t)i * 128 * 256, oF = (size_t)i * 1024 * 256;
    const size_t oSA = (size_t)i * 768 * 256;
    const size_t o256 = (size_t)i * 256, o128 = (size_t)i * 128, o1024 = (size_t)i * 1024, o768 = (size_t)i * 768;
    // self-attention (qk + v fused; qbuf_bf pre-computed by dec_init / previous ln3)
    gemm_s_sa(qbuf_bf, dout_bf, wbf + WD_SAIN + oSA, d_sa_in_b + o768, qkb, dvb, Mdec, 256);
    mha_core_kernel<<<Bc * NHc * NQc / 4, 256, 0, stream>>>(qkb, dvb, dattn_bf);
    gemm_s(dattn_bf, wbf + WD_SAOUT + oW, d_sa_out_b + o256, dproj, nullptr, Mdec, 256, 256, 0);
    // fused: qbuf_bf = f2bf(ln2_out + qpos) for cross-attention
    addln(doutb, dproj, d_ln2_g + o256, d_ln2_b + o256, dout_bf, Mdec, qpos, qbuf_bf, NQc);
    // cross (deformable) attention
    gemm_s_fused(qbuf_bf, wbf + WD_OFF + oW, d_off_b + o256, doffb,
                 wbf + WD_AW + oAW, d_aw_b + o128, dawb, Mdec, 256);
    deform_sample_kernel<<<cdiv_i(Mdec * NHc * 4, EB), EB, 0, stream>>>(
        drefb, doffb, dawb, value6_bf, dattn_bf, NQc, i * 8);  // softmax fused in-kernel
    gemm_s(dattn_bf, wbf + WD_OUT + oW, d_out_b + o256, dproj, nullptr, Mdec, 256, 256, 0);
    addln(doutb, dproj, d_ln1_g + o256, d_ln1_b + o256, dout_bf, Mdec, nullptr, nullptr, 0);
    // FFN
    gemm_s(dout_bf, wbf + WD_F1 + oF, d_f1_b + o1024, nullptr, dhid_bf, Mdec, 1024, 256, 3);
    gemm_s(dhid_bf, wbf + WD_F2 + oF, d_f2_b + o256, dproj, nullptr, Mdec, 256, 1024, 0);
    // fused: qbuf_bf = f2bf(ln3_out + qpos) for next layer's self-attention
    addln(doutb, dproj, d_ln3_g + o256, d_ln3_b + o256, dout_bf, Mdec, qpos, qbuf_bf, NQc);
  }

  store_f32_kernel<<<cdiv_i(out_size / 4, EB), EB, 0, stream>>>(doutb, (float*)d_out, out_size / 4);
}